// Round 2
// baseline (140.609 us; speedup 1.0000x reference)
//
#include <hip/hip_runtime.h>

// ---------- bf16 <-> f32 helpers (raw ushort representation) ----------
__device__ __forceinline__ float b2f(unsigned short h) {
    unsigned int u = ((unsigned int)h) << 16;
    return __builtin_bit_cast(float, u);
}
__device__ __forceinline__ unsigned short f2b(float f) {
    unsigned int u = __builtin_bit_cast(unsigned int, f);
    u += 0x7fffu + ((u >> 16) & 1u);   // round-to-nearest-even
    return (unsigned short)(u >> 16);
}

typedef short bf16x8_t __attribute__((ext_vector_type(8)));
typedef float f32x4_t  __attribute__((ext_vector_type(4)));

#define LDS_PTR(p) ((__attribute__((address_space(3))) void*)(p))
#define GLB_PTR(p) ((const __attribute__((address_space(1))) void*)(p))

// Problem dims
#define NB   16384   // batch
#define AD   1024    // A dim
#define YD   128     // output dim
#define ND   256     // GEMM N = 2*YD

// =====================================================================
// Kernel 1: Vt[n][a] = Kp[a, n>>7] * u[2a + (n>>7), n&127]   (bf16, K-major)
// =====================================================================
__global__ __launch_bounds__(256) void vt_kernel(
    const float* __restrict__ Kq,   // [1024][2] f32
    const float* __restrict__ U,    // [2048][128] f32
    unsigned short* __restrict__ Vt) // [256][1024] bf16
{
    int idx = blockIdx.x * 256 + threadIdx.x;   // 0 .. 262143
    int n = idx >> 10;
    int a = idx & 1023;
    int j = n >> 7;
    int y = n & 127;
    float k  = Kq[2 * a + j];
    float kp = k * k;
    float uv = U[(size_t)(2 * a + j) * YD + y];
    Vt[idx] = f2b(kp * uv);
}

// =====================================================================
// Kernel 2: one wave per row. 9 moments -> closed-form bf iteration ->
// write bf finals (f32) + af (bf16).
// s_j(bf) = M_j - (bf0*M_j0 + bf1*M_j1) + (bf0^2*M_j00 + 2bf0bf1*M_j01 + bf1^2*M_j11)
// =====================================================================
__global__ __launch_bounds__(256) void row_kernel(
    const float* __restrict__ AT,   // [16384][1024] f32
    const float* __restrict__ Kq,   // [1024][2] f32
    const float* __restrict__ BTv,  // [2] f32
    unsigned short* __restrict__ afb, // [16384][1024] bf16 out
    float* __restrict__ bff)        // [16384][2] f32 out
{
    int wid  = blockIdx.x * 4 + (threadIdx.x >> 6);
    int lane = threadIdx.x & 63;
    const float* at = AT + (size_t)wid * AD;

    // lane holds elements a = c*256 + lane*4 + e, c=0..3, e=0..3 (coalesced float4s)
    float ta[16], kp0[16], kp1[16];
#pragma unroll
    for (int c = 0; c < 4; ++c) {
        int base = c * 256 + lane * 4;
        float4 av = *(const float4*)(at + base);
        ta[c * 4 + 0] = av.x; ta[c * 4 + 1] = av.y;
        ta[c * 4 + 2] = av.z; ta[c * 4 + 3] = av.w;
        float4 k0 = *(const float4*)(Kq + 2 * base);      // K[a][0],K[a][1],K[a+1][0],K[a+1][1]
        float4 k1 = *(const float4*)(Kq + 2 * base + 4);  // K[a+2..a+3]
        kp0[c * 4 + 0] = k0.x * k0.x; kp1[c * 4 + 0] = k0.y * k0.y;
        kp0[c * 4 + 1] = k0.z * k0.z; kp1[c * 4 + 1] = k0.w * k0.w;
        kp0[c * 4 + 2] = k1.x * k1.x; kp1[c * 4 + 2] = k1.y * k1.y;
        kp0[c * 4 + 3] = k1.z * k1.z; kp1[c * 4 + 3] = k1.w * k1.w;
    }

    // moments: 0:M0 1:M1 2:M00 3:M01 4:M11 5:M000 6:M001 7:M011 8:M111
    float M[9];
#pragma unroll
    for (int i = 0; i < 9; ++i) M[i] = 0.f;
#pragma unroll
    for (int e = 0; e < 16; ++e) {
        float t = ta[e], p = kp0[e], q = kp1[e];
        float u0 = t * p, u1 = t * q;
        M[0] += u0; M[1] += u1;
        float u00 = u0 * p, u01 = u0 * q, u11 = u1 * q;
        M[2] += u00; M[3] += u01; M[4] += u11;
        M[5] += u00 * p; M[6] += u00 * q; M[7] += u01 * q; M[8] += u11 * q;
    }
    // wave butterfly reduce (all lanes end with full sum)
#pragma unroll
    for (int i = 0; i < 9; ++i) {
        for (int m = 1; m < 64; m <<= 1) M[i] += __shfl_xor(M[i], m, 64);
    }

    float bt0 = BTv[0], bt1 = BTv[1];
    float bf0 = 0.f, bf1 = 0.f;
#pragma unroll
    for (int it = 0; it < 8; ++it) {
        float q00 = bf0 * bf0, q01 = bf0 * bf1, q11 = bf1 * bf1;
        float s0 = M[0] - (bf0 * M[2] + bf1 * M[3]) + (q00 * M[5] + 2.f * q01 * M[6] + q11 * M[7]);
        float s1 = M[1] - (bf0 * M[3] + bf1 * M[4]) + (q00 * M[6] + 2.f * q01 * M[7] + q11 * M[8]);
        bf0 = bt0 / (1.f + s0);
        bf1 = bt1 / (1.f + s1);
    }
    if (lane == 0) { bff[(size_t)wid * 2] = bf0; bff[(size_t)wid * 2 + 1] = bf1; }

    // af = AT / (1 + bf0*kp0 + bf1*kp1), store bf16 at the same positions
    unsigned short* ao = afb + (size_t)wid * AD;
#pragma unroll
    for (int c = 0; c < 4; ++c) {
        unsigned short r[4];
#pragma unroll
        for (int e = 0; e < 4; ++e) {
            int idx = c * 4 + e;
            r[e] = f2b(ta[idx] / (1.f + bf0 * kp0[idx] + bf1 * kp1[idx]));
        }
        *(ushort4*)(ao + c * 256 + lane * 4) = make_ushort4(r[0], r[1], r[2], r[3]);
    }
}

// =====================================================================
// Kernel 3: GEMM  G[m][n] = sum_k af[m][k] * Vt[n][k]   (bf16 MFMA, fp32 out)
// BM=BN=128, BK=64, 256 threads (2x2 waves, 64x64/wave = 4x4 16x16 tiles)
// global_load_lds width=16, XOR-swizzled LDS chunks (chunk = 16B = 8 bf16).
// =====================================================================
__global__ __launch_bounds__(256) void gemm_kernel(
    const unsigned short* __restrict__ Ag,   // [16384][1024] bf16
    const unsigned short* __restrict__ Bg,   // [256][1024] bf16
    float* __restrict__ G)                   // [16384][256] f32
{
    __shared__ __align__(16) unsigned short lA[128 * 64];
    __shared__ __align__(16) unsigned short lB[128 * 64];

    const int t = threadIdx.x;
    const int lane = t & 63;
    const int wave = t >> 6;
    const int wm = wave >> 1, wn = wave & 1;
    const int mtile = blockIdx.x, ntile = blockIdx.y;

    f32x4_t acc[4][4];
#pragma unroll
    for (int i = 0; i < 4; ++i)
#pragma unroll
        for (int j = 0; j < 4; ++j) acc[i][j] = (f32x4_t){0.f, 0.f, 0.f, 0.f};

    // staging: slot s stores global chunk (m = s>>3, c = (s&7) ^ (m&7))
    const unsigned short* gA[4];
    const unsigned short* gB[4];
    int ls[4];
#pragma unroll
    for (int i = 0; i < 4; ++i) {
        int s = i * 256 + t;
        int m = s >> 3;
        int c = (s & 7) ^ (m & 7);
        gA[i] = Ag + (size_t)(mtile * 128 + m) * AD + 8 * c;
        gB[i] = Bg + (size_t)(ntile * 128 + m) * AD + 8 * c;
        ls[i] = s * 8;
    }

    for (int k0 = 0; k0 < AD; k0 += 64) {
#pragma unroll
        for (int i = 0; i < 4; ++i) {
            __builtin_amdgcn_global_load_lds(GLB_PTR(gA[i] + k0), LDS_PTR(&lA[ls[i]]), 16, 0, 0);
            __builtin_amdgcn_global_load_lds(GLB_PTR(gB[i] + k0), LDS_PTR(&lB[ls[i]]), 16, 0, 0);
        }
        __syncthreads();
#pragma unroll
        for (int kk = 0; kk < 2; ++kk) {
            const int cq = kk * 4 + (lane >> 4);
            const int rr = lane & 15;
            bf16x8_t fa[4], fb[4];
#pragma unroll
            for (int i = 0; i < 4; ++i) {
                int m = wm * 64 + i * 16 + rr;
                fa[i] = *(const bf16x8_t*)(&lA[(m * 8 + (cq ^ (m & 7))) * 8]);
                int n = wn * 64 + i * 16 + rr;
                fb[i] = *(const bf16x8_t*)(&lB[(n * 8 + (cq ^ (n & 7))) * 8]);
            }
#pragma unroll
            for (int i = 0; i < 4; ++i)
#pragma unroll
                for (int j = 0; j < 4; ++j)
                    acc[i][j] = __builtin_amdgcn_mfma_f32_16x16x32_bf16(fa[i], fb[j], acc[i][j], 0, 0, 0);
        }
        __syncthreads();
    }

    // epilogue: C/D layout col=lane&15 (n), row=(lane>>4)*4+reg (m)
    const int q = lane >> 4, col = lane & 15;
#pragma unroll
    for (int i = 0; i < 4; ++i) {
        int mg = mtile * 128 + wm * 64 + i * 16 + q * 4;
#pragma unroll
        for (int j = 0; j < 4; ++j) {
            int ng = ntile * 128 + wn * 64 + j * 16 + col;
            float* gp = G + (size_t)mg * ND + ng;
#pragma unroll
            for (int r = 0; r < 4; ++r) gp[(size_t)r * ND] = acc[i][j][r];
        }
    }
}

// =====================================================================
// Kernel 4: out[b][y] = bf0[b]*G[b][y] + bf1[b]*G[b][y+128] + bias[y]  (f32)
// =====================================================================
__global__ __launch_bounds__(256) void combine_kernel(
    const float* __restrict__ G,     // [16384][256]
    const float* __restrict__ bff,   // [16384][2]
    const float* __restrict__ bias,  // [128] f32
    float* __restrict__ out)         // [16384][128] f32
{
    int idx = blockIdx.x * 256 + threadIdx.x;   // 0 .. 16384*32-1
    int b  = idx >> 5;
    int y4 = (idx & 31) * 4;
    float bf0 = bff[2 * b], bf1 = bff[2 * b + 1];
    float4 g0 = *(const float4*)(G + (size_t)b * ND + y4);
    float4 g1 = *(const float4*)(G + (size_t)b * ND + YD + y4);
    float4 bv = *(const float4*)(bias + y4);
    float4 r;
    r.x = bf0 * g0.x + bf1 * g1.x + bv.x;
    r.y = bf0 * g0.y + bf1 * g1.y + bv.y;
    r.z = bf0 * g0.z + bf1 * g1.z + bv.z;
    r.w = bf0 * g0.w + bf1 * g1.w + bv.w;
    *(float4*)(out + (size_t)b * YD + y4) = r;
}

// =====================================================================
extern "C" void kernel_launch(void* const* d_in, const int* in_sizes, int n_in,
                              void* d_out, int out_size, void* d_ws, size_t ws_size,
                              hipStream_t stream) {
    const float* AT  = (const float*)d_in[0];  // [16384][1024] f32
    const float* Kq  = (const float*)d_in[1];  // [1024][2] f32
    const float* BTv = (const float*)d_in[2];  // [2] f32
    const float* U   = (const float*)d_in[3];  // [2048][128] f32
    const float* bia = (const float*)d_in[4];  // [128] f32
    float* out = (float*)d_out;

    char* ws = (char*)d_ws;
    unsigned short* afb = (unsigned short*)(ws);             // 32 MB  bf16 [16384][1024]
    unsigned short* Vt  = (unsigned short*)(ws + 33554432);  // 512 KB bf16 [256][1024]
    float*          G   = (float*)(ws + 34078720);           // 16 MB  f32  [16384][256]
    float*          bff = (float*)(ws + 50855936);           // 128 KB f32  [16384][2]
    // total ws usage ~48.6 MB

    vt_kernel<<<dim3(1024), dim3(256), 0, stream>>>(Kq, U, Vt);
    row_kernel<<<dim3(NB / 4), dim3(256), 0, stream>>>(AT, Kq, BTv, afb, bff);
    gemm_kernel<<<dim3(NB / 128, ND / 128), dim3(256), 0, stream>>>(afb, Vt, G);
    combine_kernel<<<dim3(NB * 32 / 256), dim3(256), 0, stream>>>(G, bff, bia, out);
}

// Round 3
// 129.844 us; speedup vs baseline: 1.0829x; 1.0829x over previous
//
#include <hip/hip_runtime.h>

// ---------- bf16 <-> f32 helpers (raw ushort representation) ----------
__device__ __forceinline__ float b2f(unsigned short h) {
    unsigned int u = ((unsigned int)h) << 16;
    return __builtin_bit_cast(float, u);
}
__device__ __forceinline__ unsigned short f2b(float f) {
    unsigned int u = __builtin_bit_cast(unsigned int, f);
    u += 0x7fffu + ((u >> 16) & 1u);   // round-to-nearest-even
    return (unsigned short)(u >> 16);
}

typedef short bf16x8_t __attribute__((ext_vector_type(8)));
typedef float f32x4_t  __attribute__((ext_vector_type(4)));

#define LDS_PTR(p) ((__attribute__((address_space(3))) void*)(p))
#define GLB_PTR(p) ((const __attribute__((address_space(1))) void*)(p))

// Problem dims
#define NB   16384   // batch
#define AD   1024    // A dim
#define YD   128     // output dim
#define ND   256     // GEMM N = 2*YD

// =====================================================================
// Kernel 1: Vt[n][a] = Kp[a, n>>7] * u[2a + (n>>7), n&127]   (bf16, K-major)
// =====================================================================
__global__ __launch_bounds__(256) void vt_kernel(
    const float* __restrict__ Kq,   // [1024][2] f32
    const float* __restrict__ U,    // [2048][128] f32
    unsigned short* __restrict__ Vt) // [256][1024] bf16
{
    int idx = blockIdx.x * 256 + threadIdx.x;   // 0 .. 262143
    int n = idx >> 10;
    int a = idx & 1023;
    int j = n >> 7;
    int y = n & 127;
    float k  = Kq[2 * a + j];
    float kp = k * k;
    float uv = U[(size_t)(2 * a + j) * YD + y];
    Vt[idx] = f2b(kp * uv);
}

// =====================================================================
// Kernel 2: one wave per row. 9 moments -> closed-form bf iteration ->
// write bf finals (f32) + af (bf16).  [validated round 2: absmax 1.56e-2]
// =====================================================================
__global__ __launch_bounds__(256) void row_kernel(
    const float* __restrict__ AT,   // [16384][1024] f32
    const float* __restrict__ Kq,   // [1024][2] f32
    const float* __restrict__ BTv,  // [2] f32
    unsigned short* __restrict__ afb, // [16384][1024] bf16 out
    float* __restrict__ bff)        // [16384][2] f32 out
{
    int wid  = blockIdx.x * 4 + (threadIdx.x >> 6);
    int lane = threadIdx.x & 63;
    const float* at = AT + (size_t)wid * AD;

    // lane holds elements a = c*256 + lane*4 + e, c=0..3, e=0..3 (coalesced float4s)
    float ta[16], kp0[16], kp1[16];
#pragma unroll
    for (int c = 0; c < 4; ++c) {
        int base = c * 256 + lane * 4;
        float4 av = *(const float4*)(at + base);
        ta[c * 4 + 0] = av.x; ta[c * 4 + 1] = av.y;
        ta[c * 4 + 2] = av.z; ta[c * 4 + 3] = av.w;
        float4 k0 = *(const float4*)(Kq + 2 * base);      // K[a][0..1],K[a+1][0..1]
        float4 k1 = *(const float4*)(Kq + 2 * base + 4);  // K[a+2..a+3]
        kp0[c * 4 + 0] = k0.x * k0.x; kp1[c * 4 + 0] = k0.y * k0.y;
        kp0[c * 4 + 1] = k0.z * k0.z; kp1[c * 4 + 1] = k0.w * k0.w;
        kp0[c * 4 + 2] = k1.x * k1.x; kp1[c * 4 + 2] = k1.y * k1.y;
        kp0[c * 4 + 3] = k1.z * k1.z; kp1[c * 4 + 3] = k1.w * k1.w;
    }

    // moments: 0:M0 1:M1 2:M00 3:M01 4:M11 5:M000 6:M001 7:M011 8:M111
    float M[9];
#pragma unroll
    for (int i = 0; i < 9; ++i) M[i] = 0.f;
#pragma unroll
    for (int e = 0; e < 16; ++e) {
        float t = ta[e], p = kp0[e], q = kp1[e];
        float u0 = t * p, u1 = t * q;
        M[0] += u0; M[1] += u1;
        float u00 = u0 * p, u01 = u0 * q, u11 = u1 * q;
        M[2] += u00; M[3] += u01; M[4] += u11;
        M[5] += u00 * p; M[6] += u00 * q; M[7] += u01 * q; M[8] += u11 * q;
    }
#pragma unroll
    for (int i = 0; i < 9; ++i) {
        for (int m = 1; m < 64; m <<= 1) M[i] += __shfl_xor(M[i], m, 64);
    }

    float bt0 = BTv[0], bt1 = BTv[1];
    float bf0 = 0.f, bf1 = 0.f;
#pragma unroll
    for (int it = 0; it < 8; ++it) {
        float q00 = bf0 * bf0, q01 = bf0 * bf1, q11 = bf1 * bf1;
        float s0 = M[0] - (bf0 * M[2] + bf1 * M[3]) + (q00 * M[5] + 2.f * q01 * M[6] + q11 * M[7]);
        float s1 = M[1] - (bf0 * M[3] + bf1 * M[4]) + (q00 * M[6] + 2.f * q01 * M[7] + q11 * M[8]);
        bf0 = bt0 / (1.f + s0);
        bf1 = bt1 / (1.f + s1);
    }
    if (lane == 0) { bff[(size_t)wid * 2] = bf0; bff[(size_t)wid * 2 + 1] = bf1; }

    unsigned short* ao = afb + (size_t)wid * AD;
#pragma unroll
    for (int c = 0; c < 4; ++c) {
        unsigned short r[4];
#pragma unroll
        for (int e = 0; e < 4; ++e) {
            int idx = c * 4 + e;
            r[e] = f2b(ta[idx] / (1.f + bf0 * kp0[idx] + bf1 * kp1[idx]));
        }
        *(ushort4*)(ao + c * 256 + lane * 4) = make_ushort4(r[0], r[1], r[2], r[3]);
    }
}

// =====================================================================
// Kernel 3: fused GEMM+combine.
//   G[m][n] = sum_k af[m][k] * Vt[n][k]  (bf16 MFMA)
//   out[m][y] = bf0[m]*G[m][y] + bf1[m]*G[m][y+128] + bias[y]
// BM=32, BN=256(full), BK=64; 512 blocks (2/CU), 256 threads (4 waves).
// Wave j-tile map ng = wn*32 + (j&1)*16 + (j>>1)*128 keeps (y, y+128)
// pairs in-register -> no epilogue exchange.
// =====================================================================
__global__ __launch_bounds__(256) void gemm_fused_kernel(
    const unsigned short* __restrict__ Ag,   // [16384][1024] bf16 (af)
    const unsigned short* __restrict__ Bg,   // [256][1024] bf16 (Vt)
    const float* __restrict__ bff,           // [16384][2]
    const float* __restrict__ bias,          // [128]
    float* __restrict__ out)                 // [16384][128] f32
{
    __shared__ __align__(16) unsigned short lA[32 * 64];    // 4 KB
    __shared__ __align__(16) unsigned short lB[256 * 64];   // 32 KB

    const int t = threadIdx.x;
    const int lane = t & 63;
    const int wn = t >> 6;          // wave id = n-group
    const int mtile = blockIdx.x;   // 0..511

    f32x4_t acc[2][4];
#pragma unroll
    for (int i = 0; i < 2; ++i)
#pragma unroll
        for (int j = 0; j < 4; ++j) acc[i][j] = (f32x4_t){0.f, 0.f, 0.f, 0.f};

    // staging slot s holds global chunk (row = s>>3, c = (s&7) ^ (row&7))
    // A: 256 slots (1/thread). B: 2048 slots (8/thread).
    const unsigned short* gA;
    const unsigned short* gB[8];
    {
        int s = t;
        int m = s >> 3;
        int c = (s & 7) ^ (m & 7);
        gA = Ag + (size_t)(mtile * 32 + m) * AD + 8 * c;
    }
#pragma unroll
    for (int i = 0; i < 8; ++i) {
        int s = i * 256 + t;
        int n = s >> 3;
        int c = (s & 7) ^ (n & 7);
        gB[i] = Bg + (size_t)n * AD + 8 * c;
    }

    for (int k0 = 0; k0 < AD; k0 += 64) {
        __builtin_amdgcn_global_load_lds(GLB_PTR(gA + k0), LDS_PTR(&lA[t * 8]), 16, 0, 0);
#pragma unroll
        for (int i = 0; i < 8; ++i)
            __builtin_amdgcn_global_load_lds(GLB_PTR(gB[i] + k0), LDS_PTR(&lB[(i * 256 + t) * 8]), 16, 0, 0);
        __syncthreads();
#pragma unroll
        for (int kk = 0; kk < 2; ++kk) {
            const int cq = kk * 4 + (lane >> 4);
            const int rr = lane & 15;
            bf16x8_t fa[2], fb[4];
#pragma unroll
            for (int i = 0; i < 2; ++i) {
                int m = i * 16 + rr;
                fa[i] = *(const bf16x8_t*)(&lA[(m * 8 + (cq ^ (m & 7))) * 8]);
            }
#pragma unroll
            for (int j = 0; j < 4; ++j) {
                int n = wn * 32 + (j & 1) * 16 + (j >> 1) * 128 + rr;
                fb[j] = *(const bf16x8_t*)(&lB[(n * 8 + (cq ^ (n & 7))) * 8]);
            }
#pragma unroll
            for (int i = 0; i < 2; ++i)
#pragma unroll
                for (int j = 0; j < 4; ++j)
                    acc[i][j] = __builtin_amdgcn_mfma_f32_16x16x32_bf16(fa[i], fb[j], acc[i][j], 0, 0, 0);
        }
        __syncthreads();
    }

    // epilogue: C/D layout col=lane&15 (n), row=(lane>>4)*4+reg (m)
    const int q = lane >> 4, col = lane & 15;
#pragma unroll
    for (int i = 0; i < 2; ++i) {
        int mbase = mtile * 32 + i * 16 + q * 4;
        float2 bfv[4];
#pragma unroll
        for (int r = 0; r < 4; ++r)
            bfv[r] = *(const float2*)(bff + (size_t)(mbase + r) * 2);
#pragma unroll
        for (int j = 0; j < 2; ++j) {
            int y = wn * 32 + j * 16 + col;
            float bv = bias[y];
#pragma unroll
            for (int r = 0; r < 4; ++r) {
                float val = bfv[r].x * acc[i][j][r] + bfv[r].y * acc[i][j + 2][r] + bv;
                out[(size_t)(mbase + r) * YD + y] = val;
            }
        }
    }
}

// =====================================================================
extern "C" void kernel_launch(void* const* d_in, const int* in_sizes, int n_in,
                              void* d_out, int out_size, void* d_ws, size_t ws_size,
                              hipStream_t stream) {
    const float* AT  = (const float*)d_in[0];  // [16384][1024] f32
    const float* Kq  = (const float*)d_in[1];  // [1024][2] f32
    const float* BTv = (const float*)d_in[2];  // [2] f32
    const float* U   = (const float*)d_in[3];  // [2048][128] f32
    const float* bia = (const float*)d_in[4];  // [128] f32
    float* out = (float*)d_out;

    char* ws = (char*)d_ws;
    unsigned short* afb = (unsigned short*)(ws);             // 32 MB  bf16 [16384][1024]
    unsigned short* Vt  = (unsigned short*)(ws + 33554432);  // 512 KB bf16 [256][1024]
    float*          bff = (float*)(ws + 34078720);           // 128 KB f32  [16384][2]
    // total ws usage ~34.2 MB

    vt_kernel<<<dim3(1024), dim3(256), 0, stream>>>(Kq, U, Vt);
    row_kernel<<<dim3(NB / 4), dim3(256), 0, stream>>>(AT, Kq, BTv, afb, bff);
    gemm_fused_kernel<<<dim3(NB / 32), dim3(256), 0, stream>>>(afb, Vt, bff, bia, out);
}